// Round 4
// baseline (879.768 us; speedup 1.0000x reference)
//
#include <hip/hip_runtime.h>

// Correlation cost volume: B=4, C=256, H=W=192, MAX_DISP=4 -> 81 displacements.
// out[b, dy*9+dx, y, x] = (1/C) * sum_c F[b,c,y,x] * Spad[b,c,y+dy-4,x+dx-4]
//
// R4: wave-autonomous blocks. 1 wave per block, 1 dy per block (grid 2592 =
//     10.1 blocks/CU), NO __syncthreads -> no convoy, no vmcnt(0) drain of the
//     global prefetch. 8 px per lane (TH=8): 4 ds_read_b128 -> 72 FMA per
//     channel (1.5x fewer LDS reads than 4-px). S rows at stride 19 float4:
//     read slot (3r+2xg+j) mod 8 is perfectly bank-balanced (8 dwords/bank).

#define MAXD 4
#define WINW 9
#define NDISP 81

constexpr int B_ = 4, C_ = 256, H_ = 192, W_ = 192;
constexpr int TH = 8;                    // tile rows (1 per lane octet)
constexpr int TW = 64;                   // tile cols (8 px per lane)
constexpr int CC = 2;                    // channels staged per chunk
constexpr int NCHUNK = C_ / CC;          // 128
constexpr int SCOLS = TW + 2 * MAXD;     // 72 staged cols
constexpr int SR = TH;                   // 8 staged rows (single dy)
constexpr int ST4 = 19;                  // float4 stride per row (76 floats)
constexpr int S_CH4 = SR * ST4;          // 152 float4 per channel
constexpr int HALF4 = CC * S_CH4;        // 304 float4 per buffer half
constexpr int NS4 = CC * SR * (SCOLS / 4);  // 288 float4 slots per chunk
constexpr int NTHREADS = 64;             // single wave

__global__ __launch_bounds__(NTHREADS, 3)
void corr_kernel(const float* __restrict__ F, const float* __restrict__ S,
                 float* __restrict__ O) {
    __shared__ __align__(16) float ldsS[2 * HALF4 * 4];   // 2432 floats, 9.7 KB

    const int lane = threadIdx.x;        // block == one wave
    const int y0   = blockIdx.x * TH;
    const int x0   = blockIdx.y * TW;
    const int zb   = blockIdx.z;         // 36 = B * 9
    const int b    = zb / WINW;
    const int dy   = zb - b * WINW;
    const int xg   = lane & 7;           // x-group of 8 px
    const int yth  = lane >> 3;          // row within tile, [0,8)

    const long planeHW   = (long)H_ * W_;          // 36864
    const long chunkStep = (long)CC * planeHW;
    const float* Fb = F + (long)b * C_ * planeHW;
    const float* Sb = S + (long)b * C_ * planeHW;

    // ---- F: direct per-thread global pointers (8 own px, in-bounds) ----
    const float* fp = Fb + (long)(y0 + yth) * W_ + (x0 + 8 * xg);

    // ---- chunk-invariant S staging decomposition: 5 slots per lane ----
    const float* sg[5];
    int  slds[5];
    bool sin_[5], sact[5];
    #pragma unroll
    for (int q = 0; q < 5; ++q) {
        const int i   = lane + q * NTHREADS;
        const bool act = (i < NS4);
        const int ii  = act ? i : 0;
        const int cc  = ii / (SR * (SCOLS / 4));            // /144
        const int rem = ii - cc * (SR * (SCOLS / 4));
        const int r   = rem / (SCOLS / 4);                  // /18
        const int cg  = rem - r * (SCOLS / 4);
        const int ys  = y0 + dy - MAXD + r;
        const int xs  = x0 - MAXD + 4 * cg;
        sact[q] = act;
        sin_[q] = act && ((unsigned)ys < (unsigned)H_) &&
                         ((unsigned)xs <= (unsigned)(W_ - 4));
        slds[q] = cc * S_CH4 + r * ST4 + cg;                // float4 index
        sg[q]   = Sb + (long)cc * planeHW + (long)ys * W_ + xs;
    }

    // ---- zero OOB halo slots ONCE (both halves) ----
    const float4 z4 = make_float4(0.f, 0.f, 0.f, 0.f);
    #pragma unroll
    for (int q = 0; q < 5; ++q) {
        if (sact[q] && !sin_[q]) {
            *(float4*)(ldsS + 4 * slds[q])           = z4;
            *(float4*)(ldsS + 4 * (slds[q] + HALF4)) = z4;
        }
    }

    // ---- S pipeline: register prefetch + double-buffered LDS ----
    float4 ps[5];
    auto loadS = [&]() {
        #pragma unroll
        for (int q = 0; q < 5; ++q) {
            if (sin_[q]) ps[q] = *(const float4*)sg[q];
            sg[q] += chunkStep;
        }
    };
    auto writeS = [&](int half) {
        float* wS = ldsS + half * (HALF4 * 4);
        #pragma unroll
        for (int q = 0; q < 5; ++q)
            if (sin_[q]) *(float4*)(wS + 4 * slds[q]) = ps[q];
    };

    // ---- accumulators: 9 dx x 8 px ----
    float acc[WINW][8];
    #pragma unroll
    for (int dx = 0; dx < WINW; ++dx)
        #pragma unroll
        for (int p = 0; p < 8; ++p) acc[dx][p] = 0.f;

    // prologue: chunk 0 staged, chunk 1 in regs
    loadS();
    writeS(0);
    loadS();

    const int rdBase = yth * ST4 + 2 * xg;   // float4 index within channel

    for (int k = 0; k < NCHUNK; ++k) {
        // F for chunk k: 4 global b128 (shared with 8 other dy-waves via L1/L2)
        const float4 fA0 = *(const float4*)(fp);
        const float4 fA1 = *(const float4*)(fp + 4);
        const float4 fB0 = *(const float4*)(fp + planeHW);
        const float4 fB1 = *(const float4*)(fp + planeHW + 4);
        fp += chunkStep;

        // cross-lane visibility of the writes from iteration k-1 (long done);
        // wave-local in-order DS + this wait replaces __syncthreads entirely.
        asm volatile("s_waitcnt lgkmcnt(0)" ::: "memory");

        const float* hb = ldsS + (k & 1) * (HALF4 * 4);
        #pragma unroll
        for (int cc = 0; cc < CC; ++cc) {
            const float* rb = hb + 4 * (cc * S_CH4 + rdBase);
            const float4 w0 = *(const float4*)(rb);
            const float4 w1 = *(const float4*)(rb + 4);
            const float4 w2 = *(const float4*)(rb + 8);
            const float4 w3 = *(const float4*)(rb + 12);
            const float w[16] = {w0.x, w0.y, w0.z, w0.w, w1.x, w1.y, w1.z, w1.w,
                                 w2.x, w2.y, w2.z, w2.w, w3.x, w3.y, w3.z, w3.w};
            const float4 f0 = cc ? fB0 : fA0;
            const float4 f1 = cc ? fB1 : fA1;
            const float f[8] = {f0.x, f0.y, f0.z, f0.w, f1.x, f1.y, f1.z, f1.w};
            #pragma unroll
            for (int dx = 0; dx < WINW; ++dx)
                #pragma unroll
                for (int p = 0; p < 8; ++p)
                    acc[dx][p] += f[p] * w[dx + p];
        }

        // stage chunk k+1 (regs -> other half), then issue chunk k+2 loads
        if (k + 1 < NCHUNK) {
            writeS((k + 1) & 1);
            if (k + 2 < NCHUNK) loadS();
        }
    }

    // ---- epilogue: 9 x 2 coalesced float4 stores ----
    const float scale = 1.0f / (float)C_;
    #pragma unroll
    for (int dx = 0; dx < WINW; ++dx) {
        float4 oA, oB;
        oA.x = acc[dx][0] * scale;  oA.y = acc[dx][1] * scale;
        oA.z = acc[dx][2] * scale;  oA.w = acc[dx][3] * scale;
        oB.x = acc[dx][4] * scale;  oB.y = acc[dx][5] * scale;
        oB.z = acc[dx][6] * scale;  oB.w = acc[dx][7] * scale;
        const int d = dy * WINW + dx;
        float* dst = O + ((long)(b * NDISP + d) * H_ + (y0 + yth)) * W_
                       + x0 + 8 * xg;
        *(float4*)dst       = oA;
        *(float4*)(dst + 4) = oB;
    }
}

extern "C" void kernel_launch(void* const* d_in, const int* in_sizes, int n_in,
                              void* d_out, int out_size, void* d_ws, size_t ws_size,
                              hipStream_t stream) {
    const float* F = (const float*)d_in[0];
    const float* S = (const float*)d_in[1];
    float* O = (float*)d_out;
    dim3 grid(H_ / TH, W_ / TW, B_ * WINW);   // 24 x 3 x 36 = 2592 blocks
    dim3 block(NTHREADS);
    corr_kernel<<<grid, block, 0, stream>>>(F, S, O);
}

// Round 5
// 515.436 us; speedup vs baseline: 1.7068x; 1.7068x over previous
//
#include <hip/hip_runtime.h>

// Correlation cost volume: B=4, C=256, H=W=192, MAX_DISP=4 -> 81 displacements.
// out[b, dy*9+dx, y, x] = (1/C) * sum_c F[b,c,y,x] * Spad[b,c,y+dy-4,x+dx-4]
//
// R5: NO LDS. Each lane loads its 12-float S window directly from global
//     (3 overlapping b128) + its 4 F px (1 b128) per channel; 1-deep register
//     prefetch; single-wave blocks (no barriers at all). 9x dy-redundant
//     reads are served by per-XCD L2 via a bijective swizzle that puts all
//     36 (b,dy) variants of a tile on one XCD (5184 = 8 x 18 tiles x 36).
//     R4 lesson: keep the no-spill shape (36 acc + 12 w + 4 f, VGPR<=128).
//     Halo float4s are all-or-nothing valid (4-aligned); invalid lanes load
//     a clamped address and the exactly-zero outputs are fixed in epilogue.

#define MAXD 4
#define WINW 9
#define NDISP 81

constexpr int B_ = 4, C_ = 256, H_ = 192, W_ = 192;
constexpr int TH = 4, TW = 64;
constexpr int NTX = W_ / TW;           // 3
constexpr int NTY = H_ / TH;           // 48
constexpr int NTILE = NTX * NTY;       // 144
constexpr int NZ = B_ * WINW;          // 36
constexpr int NBLK = NTILE * NZ;       // 5184
constexpr int PER_XCD = NBLK / 8;      // 648 (= 18 tiles x 36, exact)
constexpr int PHW = H_ * W_;           // 36864

__global__ __launch_bounds__(64, 4)
void corr_kernel(const float* __restrict__ F, const float* __restrict__ S,
                 float* __restrict__ O) {
    const int lane = threadIdx.x;
    const int xg   = lane & 15;          // x-group of 4 px
    const int yth  = lane >> 4;          // row within tile [0,4)

    // ---- XCD-bijective block swizzle: XCD k owns tiles [18k, 18k+18) with
    //      all 36 (b,dy) variants dispatch-adjacent -> dy-redundancy is L2-local.
    const int id   = blockIdx.x;
    const int lg   = (id & 7) * PER_XCD + (id >> 3);
    const int tile = lg / NZ;
    const int zb   = lg - tile * NZ;
    const int b    = zb / WINW;
    const int dy   = zb - b * WINW;
    const int ty   = tile / NTX;
    const int tx   = tile - ty * NTX;
    const int y0 = ty * TH, x0 = tx * TW;

    const float* Fb = F + (long)b * C_ * PHW;
    const float* Sb = S + (long)b * C_ * PHW;

    const int  fRow  = y0 + yth;                       // output/F row
    const int  sRow  = fRow + dy - MAXD;               // S row for this dy
    const bool rowOK = ((unsigned)sRow < (unsigned)H_);
    const int  sRowC = rowOK ? sRow : 0;               // clamped (safe addr)
    const int  sxb   = x0 + 4 * xg - MAXD;             // window start col
    const int  xout  = x0 + 4 * xg;                    // output col

    // three S float4s per channel; each is entirely in- or out-of-range.
    // invalid ones load from col 0 (safe) and are zeroed in the epilogue.
    unsigned oF = (unsigned)(fRow * W_ + xout);
    unsigned o0 = (unsigned)(sRowC * W_ + (sxb >= 0 ? sxb : 0));
    unsigned o1 = (unsigned)(sRowC * W_ + sxb + 4);            // always valid
    unsigned o2 = (unsigned)(sRowC * W_ + (sxb <= W_ - 12 ? sxb + 8 : 0));

    float acc[WINW][4];
    #pragma unroll
    for (int dx = 0; dx < WINW; ++dx)
        #pragma unroll
        for (int j = 0; j < 4; ++j) acc[dx][j] = 0.f;

    // ---- prologue: channel 0 in registers ----
    float4 cf = *(const float4*)(Fb + oF);
    float4 c0 = *(const float4*)(Sb + o0);
    float4 c1 = *(const float4*)(Sb + o1);
    float4 c2 = *(const float4*)(Sb + o2);
    oF += PHW; o0 += PHW; o1 += PHW; o2 += PHW;

    auto fma12 = [&](const float4& f4, const float4& a, const float4& bb,
                     const float4& c) {
        const float w[12] = {a.x,  a.y,  a.z,  a.w,
                             bb.x, bb.y, bb.z, bb.w,
                             c.x,  c.y,  c.z,  c.w};
        const float f[4]  = {f4.x, f4.y, f4.z, f4.w};
        #pragma unroll
        for (int dx = 0; dx < WINW; ++dx)
            #pragma unroll
            for (int j = 0; j < 4; ++j)
                acc[dx][j] += f[j] * w[dx + j];
    };

    // ---- main loop: prefetch channel c+1 while computing channel c ----
    #pragma unroll 2
    for (int c = 0; c < C_ - 1; ++c) {
        const float4 nf = *(const float4*)(Fb + oF);
        const float4 n0 = *(const float4*)(Sb + o0);
        const float4 n1 = *(const float4*)(Sb + o1);
        const float4 n2 = *(const float4*)(Sb + o2);
        oF += PHW; o0 += PHW; o1 += PHW; o2 += PHW;

        fma12(cf, c0, c1, c2);

        cf = nf; c0 = n0; c1 = n1; c2 = n2;
    }
    fma12(cf, c0, c1, c2);   // last channel

    // ---- epilogue: scale, zero the exactly-zero (padded) outputs, store ----
    const float scale = 1.0f / (float)C_;
    #pragma unroll
    for (int dx = 0; dx < WINW; ++dx) {
        float ov[4];
        #pragma unroll
        for (int j = 0; j < 4; ++j) {
            const int sc = xout + j + dx - MAXD;   // S col this output samples
            const bool ok = rowOK && ((unsigned)sc < (unsigned)W_);
            ov[j] = ok ? acc[dx][j] * scale : 0.f;
        }
        const int d = dy * WINW + dx;
        float* dst = O + ((long)(b * NDISP + d) * H_ + fRow) * W_ + xout;
        *(float4*)dst = make_float4(ov[0], ov[1], ov[2], ov[3]);
    }
}

extern "C" void kernel_launch(void* const* d_in, const int* in_sizes, int n_in,
                              void* d_out, int out_size, void* d_ws, size_t ws_size,
                              hipStream_t stream) {
    const float* F = (const float*)d_in[0];
    const float* S = (const float*)d_in[1];
    float* O = (float*)d_out;
    dim3 grid(NBLK, 1, 1);   // 5184 single-wave blocks
    dim3 block(64);
    corr_kernel<<<grid, block, 0, stream>>>(F, S, O);
}

// Round 6
// 513.537 us; speedup vs baseline: 1.7132x; 1.0037x over previous
//
#include <hip/hip_runtime.h>

// Correlation cost volume: B=4, C=256, H=W=192, MAX_DISP=4 -> 81 displacements.
// out[b, dy*9+dx, y, x] = (1/C) * sum_c F[b,c,y,x] * Spad[b,c,y+dy-4,x+dx-4]
//
// R6: no-LDS (R5) + DPP neighbor-exchange. Each lane loads ONE aligned S quad
//     per channel; the left/right window quads come from lanes xg-1/xg+1 via
//     v_mov_dpp row_shr:1 / row_shl:1 (DPP 16-lane rows == our xg rows).
//     Boundary lanes get their halo quad from a 1-line masked load passed as
//     the DPP 'old' operand (bound_ctrl=false keeps old on invalid lanes).
//     4-wave blocks (256 thr) fix R5's single-wave WG occupancy cap (37%).
//     Edge-garbage in halos is masked by the epilogue's exact-zero rule.

#define MAXD 4
#define WINW 9
#define NDISP 81

constexpr int B_ = 4, C_ = 256, H_ = 192, W_ = 192;
constexpr int TH = 16, TW = 64;        // block tile: 16 rows x 64 cols (4 waves)
constexpr int NTX = W_ / TW;           // 3
constexpr int NTY = H_ / TH;           // 12
constexpr int NZ = B_ * WINW;          // 36
constexpr int NBLK = NTX * NTY * NZ;   // 1296 blocks
constexpr int PER_XCD = NBLK / 8;      // 162 (exact)
constexpr int PHW = H_ * W_;           // 36864
constexpr int NTHREADS = 256;

// row_shr:1 = 0x111: dst[n] = src[n-1] within each 16-lane row (left neighbor)
// row_shl:1 = 0x101: dst[n] = src[n+1] within each 16-lane row (right neighbor)
// bound_ctrl=false: invalid source lane -> dst keeps 'old' (our halo value).
template <int CTRL>
__device__ __forceinline__ float dpp_mov(float oldv, float srcv) {
    return __int_as_float(__builtin_amdgcn_update_dpp(
        __float_as_int(oldv), __float_as_int(srcv), CTRL, 0xF, 0xF, false));
}

__global__ __launch_bounds__(NTHREADS, 4)
void corr_kernel(const float* __restrict__ F, const float* __restrict__ S,
                 float* __restrict__ O) {
    const int tid = threadIdx.x;
    const int xg  = tid & 15;            // x-group of 4 px; DPP row position
    const int ryi = tid >> 4;            // row within 16-row tile [0,16)

    // ---- XCD-bijective swizzle: 1296 = 8 x 162; z (b,dy) fastest so all 36
    //      variants of a tile region are dispatch-adjacent on one XCD.
    const int id   = blockIdx.x;
    const int lg   = (id & 7) * PER_XCD + (id >> 3);
    const int tile = lg / NZ;
    const int zb   = lg - tile * NZ;
    const int b    = zb / WINW;
    const int dy   = zb - b * WINW;
    const int ty   = tile / NTX;
    const int tx   = tile - ty * NTX;
    const int y0 = ty * TH, x0 = tx * TW;

    const float* Fb = F + (long)b * C_ * PHW;
    const float* Sb = S + (long)b * C_ * PHW;

    const int  fRow  = y0 + ryi;                 // output/F row
    const int  xout  = x0 + 4 * xg;              // output col (4-aligned)
    const int  sRow  = fRow + dy - MAXD;
    const bool rowOK = ((unsigned)sRow < (unsigned)H_);
    const int  sRowC = rowOK ? sRow : 0;         // clamped safe row

    // halo column: xg==0 -> left halo quad, xg==15 -> right halo quad.
    // Clamped when outside the image; garbage is epilogue-masked.
    int hx = xout;
    if (xg == 0)  hx = (x0 >= 4) ? (x0 - 4) : 0;
    if (xg == 15) hx = (x0 + TW <= W_ - 4) ? (x0 + TW) : (W_ - 4);

    const float* pF = Fb + (long)fRow * W_ + xout;   // own F quad
    const float* pS = Sb + (long)sRowC * W_ + xout;  // own S quad
    const float* pH = Sb + (long)sRowC * W_ + hx;    // halo quad (1 line)

    float acc[WINW][4];
    #pragma unroll
    for (int dx = 0; dx < WINW; ++dx)
        #pragma unroll
        for (int j = 0; j < 4; ++j) acc[dx][j] = 0.f;

    auto step = [&](const float4& f4, const float4& s4, const float4& h4) {
        float wv[12];
        // left quad: from lane xg-1 (row_shr:1); xg==0 keeps old = halo
        wv[0] = dpp_mov<0x111>(h4.x, s4.x);
        wv[1] = dpp_mov<0x111>(h4.y, s4.y);
        wv[2] = dpp_mov<0x111>(h4.z, s4.z);
        wv[3] = dpp_mov<0x111>(h4.w, s4.w);
        // own quad
        wv[4] = s4.x; wv[5] = s4.y; wv[6] = s4.z; wv[7] = s4.w;
        // right quad: from lane xg+1 (row_shl:1); xg==15 keeps old = halo
        wv[8]  = dpp_mov<0x101>(h4.x, s4.x);
        wv[9]  = dpp_mov<0x101>(h4.y, s4.y);
        wv[10] = dpp_mov<0x101>(h4.z, s4.z);
        wv[11] = dpp_mov<0x101>(h4.w, s4.w);
        const float f[4] = {f4.x, f4.y, f4.z, f4.w};
        #pragma unroll
        for (int dx = 0; dx < WINW; ++dx)
            #pragma unroll
            for (int j = 0; j < 4; ++j)
                acc[dx][j] += f[j] * wv[dx + j];
    };

    // ---- prologue: channel 0 in registers ----
    float4 cF = *(const float4*)pF;
    float4 cS = *(const float4*)pS;
    float4 cH = *(const float4*)pH;
    pF += PHW; pS += PHW; pH += PHW;

    // ---- main loop: 1-deep register prefetch, no LDS, no barriers ----
    #pragma unroll 2
    for (int c = 0; c < C_ - 1; ++c) {
        const float4 nF = *(const float4*)pF;
        const float4 nS = *(const float4*)pS;
        const float4 nH = *(const float4*)pH;
        pF += PHW; pS += PHW; pH += PHW;

        step(cF, cS, cH);

        cF = nF; cS = nS; cH = nH;
    }
    step(cF, cS, cH);

    // ---- epilogue: scale; force exact zeros where S sample is out of range
    //      (also masks any clamped/garbage halo contributions) ----
    const float scale = 1.0f / (float)C_;
    #pragma unroll
    for (int dx = 0; dx < WINW; ++dx) {
        float ov[4];
        #pragma unroll
        for (int j = 0; j < 4; ++j) {
            const int sc = xout + j + dx - MAXD;
            const bool ok = rowOK && ((unsigned)sc < (unsigned)W_);
            ov[j] = ok ? acc[dx][j] * scale : 0.f;
        }
        const int d = dy * WINW + dx;
        float* dst = O + ((long)(b * NDISP + d) * H_ + fRow) * W_ + xout;
        *(float4*)dst = make_float4(ov[0], ov[1], ov[2], ov[3]);
    }
}

extern "C" void kernel_launch(void* const* d_in, const int* in_sizes, int n_in,
                              void* d_out, int out_size, void* d_ws, size_t ws_size,
                              hipStream_t stream) {
    const float* F = (const float*)d_in[0];
    const float* S = (const float*)d_in[1];
    float* O = (float*)d_out;
    dim3 grid(NBLK, 1, 1);   // 1296 four-wave blocks
    dim3 block(NTHREADS);
    corr_kernel<<<grid, block, 0, stream>>>(F, S, O);
}

// Round 7
// 487.459 us; speedup vs baseline: 1.8048x; 1.0535x over previous
//
#include <hip/hip_runtime.h>

// Correlation cost volume: B=4, C=256, H=W=192, MAX_DISP=4 -> 81 displacements.
// out[b, dy*9+dx, y, x] = (1/C) * sum_c F[b,c,y,x] * Spad[b,c,y+dy-4,x+dx-4]
//
// R7 = R6 (no-LDS + DPP neighbor-exchange, verified) with prefetch depth 1->3.
//     R5/R6 both pinned at ~315us with ~3 outstanding loads/wave: exposed
//     L2/L3 latency (Little's law). 3-stage pipeline = 9 loads in flight/wave
//     -> latency covered, kernel should flip to VALU-issue-bound.
//     VGPR watch (R4 lesson): ~100 est, cap 128 via launch_bounds(256,4);
//     spill tripwire = WRITE_SIZE must stay 46,656 KB.

#define MAXD 4
#define WINW 9
#define NDISP 81

constexpr int B_ = 4, C_ = 256, H_ = 192, W_ = 192;
constexpr int TH = 16, TW = 64;        // block tile: 16 rows x 64 cols (4 waves)
constexpr int NTX = W_ / TW;           // 3
constexpr int NTY = H_ / TH;           // 12
constexpr int NZ = B_ * WINW;          // 36
constexpr int NBLK = NTX * NTY * NZ;   // 1296 blocks
constexpr int PER_XCD = NBLK / 8;      // 162 (exact)
constexpr int PHW = H_ * W_;           // 36864
constexpr int NTHREADS = 256;

// row_shr:1 = 0x111: dst[n] = src[n-1] within each 16-lane row (left neighbor)
// row_shl:1 = 0x101: dst[n] = src[n+1] within each 16-lane row (right neighbor)
// bound_ctrl=false: invalid source lane -> dst keeps 'old' (our halo value).
template <int CTRL>
__device__ __forceinline__ float dpp_mov(float oldv, float srcv) {
    return __int_as_float(__builtin_amdgcn_update_dpp(
        __float_as_int(oldv), __float_as_int(srcv), CTRL, 0xF, 0xF, false));
}

__global__ __launch_bounds__(NTHREADS, 4)
void corr_kernel(const float* __restrict__ F, const float* __restrict__ S,
                 float* __restrict__ O) {
    const int tid = threadIdx.x;
    const int xg  = tid & 15;            // x-group of 4 px; DPP row position
    const int ryi = tid >> 4;            // row within 16-row tile [0,16)

    // ---- XCD-bijective swizzle: all 36 (b,dy) variants of a tile region are
    //      dispatch-adjacent on one XCD -> dy-redundancy served by its L2.
    const int id   = blockIdx.x;
    const int lg   = (id & 7) * PER_XCD + (id >> 3);
    const int tile = lg / NZ;
    const int zb   = lg - tile * NZ;
    const int b    = zb / WINW;
    const int dy   = zb - b * WINW;
    const int ty   = tile / NTX;
    const int tx   = tile - ty * NTX;
    const int y0 = ty * TH, x0 = tx * TW;

    const float* Fb = F + (long)b * C_ * PHW;
    const float* Sb = S + (long)b * C_ * PHW;

    const int  fRow  = y0 + ryi;                 // output/F row
    const int  xout  = x0 + 4 * xg;              // output col (4-aligned)
    const int  sRow  = fRow + dy - MAXD;
    const bool rowOK = ((unsigned)sRow < (unsigned)H_);
    const int  sRowC = rowOK ? sRow : 0;         // clamped safe row

    // halo column: xg==0 -> left halo quad, xg==15 -> right halo quad.
    // Clamped when outside the image; garbage is epilogue-masked.
    int hx = xout;
    if (xg == 0)  hx = (x0 >= 4) ? (x0 - 4) : 0;
    if (xg == 15) hx = (x0 + TW <= W_ - 4) ? (x0 + TW) : (W_ - 4);

    unsigned oF = (unsigned)(fRow * W_ + xout);
    unsigned oS = (unsigned)(sRowC * W_ + xout);
    unsigned oH = (unsigned)(sRowC * W_ + hx);

    float acc[WINW][4];
    #pragma unroll
    for (int dx = 0; dx < WINW; ++dx)
        #pragma unroll
        for (int j = 0; j < 4; ++j) acc[dx][j] = 0.f;

    auto step = [&](const float4& f4, const float4& s4, const float4& h4) {
        float wv[12];
        // left quad: from lane xg-1 (row_shr:1); xg==0 keeps old = halo
        wv[0] = dpp_mov<0x111>(h4.x, s4.x);
        wv[1] = dpp_mov<0x111>(h4.y, s4.y);
        wv[2] = dpp_mov<0x111>(h4.z, s4.z);
        wv[3] = dpp_mov<0x111>(h4.w, s4.w);
        // own quad
        wv[4] = s4.x; wv[5] = s4.y; wv[6] = s4.z; wv[7] = s4.w;
        // right quad: from lane xg+1 (row_shl:1); xg==15 keeps old = halo
        wv[8]  = dpp_mov<0x101>(h4.x, s4.x);
        wv[9]  = dpp_mov<0x101>(h4.y, s4.y);
        wv[10] = dpp_mov<0x101>(h4.z, s4.z);
        wv[11] = dpp_mov<0x101>(h4.w, s4.w);
        #pragma unroll
        for (int dx = 0; dx < WINW; ++dx) {
            acc[dx][0] += f4.x * wv[dx + 0];
            acc[dx][1] += f4.y * wv[dx + 1];
            acc[dx][2] += f4.z * wv[dx + 2];
            acc[dx][3] += f4.w * wv[dx + 3];
        }
    };

    // ---- 3-stage software pipeline: 9 loads in flight per wave ----
    float4 fA = *(const float4*)(Fb + oF);
    float4 sA = *(const float4*)(Sb + oS);
    float4 hA = *(const float4*)(Sb + oH);
    oF += PHW; oS += PHW; oH += PHW;
    float4 fB = *(const float4*)(Fb + oF);
    float4 sB = *(const float4*)(Sb + oS);
    float4 hB = *(const float4*)(Sb + oH);
    oF += PHW; oS += PHW; oH += PHW;
    float4 fC = *(const float4*)(Fb + oF);
    float4 sC = *(const float4*)(Sb + oS);
    float4 hC = *(const float4*)(Sb + oH);
    oF += PHW; oS += PHW; oH += PHW;

    // channels 0..254 in 85 groups of 3; channel 255 drains stage A after.
    for (int g = 0; g < 85; ++g) {
        step(fA, sA, hA);
        if (3 * g + 3 < C_) {
            fA = *(const float4*)(Fb + oF);
            sA = *(const float4*)(Sb + oS);
            hA = *(const float4*)(Sb + oH);
            oF += PHW; oS += PHW; oH += PHW;
        }
        step(fB, sB, hB);
        if (3 * g + 4 < C_) {
            fB = *(const float4*)(Fb + oF);
            sB = *(const float4*)(Sb + oS);
            hB = *(const float4*)(Sb + oH);
            oF += PHW; oS += PHW; oH += PHW;
        }
        step(fC, sC, hC);
        if (3 * g + 5 < C_) {
            fC = *(const float4*)(Fb + oF);
            sC = *(const float4*)(Sb + oS);
            hC = *(const float4*)(Sb + oH);
            oF += PHW; oS += PHW; oH += PHW;
        }
    }
    step(fA, sA, hA);   // channel 255

    // ---- epilogue: scale; force exact zeros where S sample is out of range
    //      (also masks any clamped/garbage halo contributions) ----
    const float scale = 1.0f / (float)C_;
    #pragma unroll
    for (int dx = 0; dx < WINW; ++dx) {
        float ov[4];
        #pragma unroll
        for (int j = 0; j < 4; ++j) {
            const int sc = xout + j + dx - MAXD;
            const bool ok = rowOK && ((unsigned)sc < (unsigned)W_);
            ov[j] = ok ? acc[dx][j] * scale : 0.f;
        }
        const int d = dy * WINW + dx;
        float* dst = O + ((long)(b * NDISP + d) * H_ + fRow) * W_ + xout;
        *(float4*)dst = make_float4(ov[0], ov[1], ov[2], ov[3]);
    }
}

extern "C" void kernel_launch(void* const* d_in, const int* in_sizes, int n_in,
                              void* d_out, int out_size, void* d_ws, size_t ws_size,
                              hipStream_t stream) {
    const float* F = (const float*)d_in[0];
    const float* S = (const float*)d_in[1];
    float* O = (float*)d_out;
    dim3 grid(NBLK, 1, 1);   // 1296 four-wave blocks
    dim3 block(NTHREADS);
    corr_kernel<<<grid, block, 0, stream>>>(F, S, O);
}

// Round 8
// 393.645 us; speedup vs baseline: 2.2349x; 1.2383x over previous
//
#include <hip/hip_runtime.h>

// Correlation cost volume: B=4, C=256, H=W=192, MAX_DISP=4 -> 81 displacements.
// out[b, dy*9+dx, y, x] = (1/C) * sum_c F[b,c,y,x] * Spad[b,c,y+dy-4,x+dx-4]
//
// R8 = R3 (best measured: 187us dispatch; 3-wave dy-split blocks, S in
//     double-buffered LDS, F global-direct) + two grafts proven in R5-R7:
//     (a) DPP neighbor-exchange (R6-verified): per channel each lane does
//         2 ds_read_b128 (own quad + halo quad) instead of 3; left/right
//         window quads come from lanes xg-/+1 via v_mov_dpp row_shr/shl:1
//         with the halo read as the 'old' operand. LDS-read term -33%,
//         bank-balanced (R3's conflict source removed).
//     (b) XCD-bijective block swizzle (R6/R7-verified): 1728 = 8 x 216; all
//         12 (b,dyg) variants of a tile dispatch-adjacent on one XCD.

#define MAXD 4
#define WINW 9
#define NDISP 81

constexpr int B_ = 4, C_ = 256, H_ = 192, W_ = 192;
constexpr int TH = 4;                    // output rows per block
constexpr int TW = 64;                   // output cols per block
constexpr int DYS = 3;                   // dy values per block
constexpr int NDY = WINW / DYS;          // 3 dy groups
constexpr int CC = 4;                    // channels staged per chunk
constexpr int NCHUNK = C_ / CC;          // 64
constexpr int SROWS = TH + DYS - 1;      // 6 staged S rows
constexpr int SCOLS = TW + 2 * MAXD;     // 72
constexpr int S_STRIDE = 72;             // floats per staged row (18 quads)
constexpr int S_CH = SROWS * S_STRIDE;   // 432 floats per staged channel
constexpr int SBUF = CC * S_CH;          // 1728 floats per half
constexpr int NTHREADS = 64 * DYS;       // 192 threads = 3 waves
constexpr int NS4 = CC * SROWS * (SCOLS / 4);   // 432 float4 per chunk
constexpr int Q_CH = SROWS * (SCOLS / 4);       // 108 float4 per channel
constexpr int NTX = W_ / TW;             // 3
constexpr int NTY = H_ / TH;             // 48
constexpr int NZ = B_ * NDY;             // 12
constexpr int NBLK = NTX * NTY * NZ;     // 1728
constexpr int PER_XCD = NBLK / 8;        // 216 (exact)
constexpr int PHW = H_ * W_;             // 36864

// row_shr:1 = 0x111: dst[n] = src[n-1] within each 16-lane row (left neighbor)
// row_shl:1 = 0x101: dst[n] = src[n+1] within each 16-lane row (right neighbor)
// bound_ctrl=false: invalid source lane -> dst keeps 'old' (our halo value).
template <int CTRL>
__device__ __forceinline__ float dpp_mov(float oldv, float srcv) {
    return __int_as_float(__builtin_amdgcn_update_dpp(
        __float_as_int(oldv), __float_as_int(srcv), CTRL, 0xF, 0xF, false));
}

__global__ __launch_bounds__(NTHREADS)
void corr_kernel(const float* __restrict__ F, const float* __restrict__ S,
                 float* __restrict__ O) {
    __shared__ __align__(16) float ldsS[2 * SBUF];   // 13.8 KB

    const int tid  = threadIdx.x;

    // ---- XCD-bijective swizzle: XCD k owns 18 tiles x 12 z-variants ----
    const int id   = blockIdx.x;
    const int lg   = (id & 7) * PER_XCD + (id >> 3);
    const int tile = lg / NZ;
    const int zb   = lg - tile * NZ;
    const int b    = zb / NDY;           // batch
    const int d0   = (zb - b * NDY) * DYS;  // first dy of this block
    const int ty   = tile / NTX;
    const int tx   = tile - ty * NTX;
    const int y0 = ty * TH, x0 = tx * TW;

    const int widx = tid >> 6;           // wave index: dy = d0 + widx
    const int lane = tid & 63;
    const int xg   = lane & 15;          // x-group of 4 px; DPP row position
    const int yth  = lane >> 4;          // row within tile, [0,4)

    const long planeHW   = (long)PHW;
    const long chunkStep = (long)CC * planeHW;
    const float* Fb = F + (long)b * C_ * planeHW;
    const float* Sb = S + (long)b * C_ * planeHW;

    // ---- F: direct per-thread global pointer (same px for all 3 waves) ----
    const float* fp = Fb + (long)(y0 + yth) * W_ + (x0 + 4 * xg);

    // ---- chunk-invariant S staging decomposition (3 slots / thread) ----
    const int ybase = y0 + d0 - MAXD;    // first staged S row

    // slot 0: i = tid (always active)
    const int  s0cc  = tid / Q_CH;
    const int  s0rem = tid - s0cc * Q_CH;
    const int  s0r   = s0rem / (SCOLS / 4);
    const int  s0cg  = s0rem - s0r * (SCOLS / 4);
    const int  s0ys  = ybase + s0r;
    const int  s0xs  = x0 - MAXD + 4 * s0cg;
    const bool s0In  = ((unsigned)s0ys < (unsigned)H_) &&
                       ((unsigned)s0xs <= (unsigned)(W_ - 4));
    const int  s0Lds = s0cc * S_CH + s0r * S_STRIDE + 4 * s0cg;
    const float* s0Ptr0 = Sb + (long)s0cc * planeHW + (long)s0ys * W_ + s0xs;

    // slot 1: i = tid + 192 (always active: i in [192,384) < 432)
    const int  i1    = tid + NTHREADS;
    const int  s1cc  = i1 / Q_CH;
    const int  s1rem = i1 - s1cc * Q_CH;
    const int  s1r   = s1rem / (SCOLS / 4);
    const int  s1cg  = s1rem - s1r * (SCOLS / 4);
    const int  s1ys  = ybase + s1r;
    const int  s1xs  = x0 - MAXD + 4 * s1cg;
    const bool s1In  = ((unsigned)s1ys < (unsigned)H_) &&
                       ((unsigned)s1xs <= (unsigned)(W_ - 4));
    const int  s1Lds = s1cc * S_CH + s1r * S_STRIDE + 4 * s1cg;
    const float* s1Ptr0 = Sb + (long)s1cc * planeHW + (long)s1ys * W_ + s1xs;

    // slot 2: i = tid + 384, active for tid < 48
    const int  i2    = tid + 2 * NTHREADS;
    const bool s2Act = (i2 < NS4);
    const int  s2cc  = i2 / Q_CH;
    const int  s2rem = i2 - s2cc * Q_CH;
    const int  s2r   = s2rem / (SCOLS / 4);
    const int  s2cg  = s2rem - s2r * (SCOLS / 4);
    const int  s2ys  = ybase + s2r;
    const int  s2xs  = x0 - MAXD + 4 * s2cg;
    const bool s2In  = s2Act && ((unsigned)s2ys < (unsigned)H_) &&
                       ((unsigned)s2xs <= (unsigned)(W_ - 4));
    const int  s2Lds = s2cc * S_CH + s2r * S_STRIDE + 4 * s2cg;
    const float* s2Ptr0 = Sb + (long)s2cc * planeHW + (long)s2ys * W_ + s2xs;

    // ---- zero the OOB halo slots ONCE (both halves) ----
    const float4 z4 = make_float4(0.f, 0.f, 0.f, 0.f);
    if (!s0In) {
        *(float4*)(ldsS + s0Lds) = z4;
        *(float4*)(ldsS + SBUF + s0Lds) = z4;
    }
    if (!s1In) {
        *(float4*)(ldsS + s1Lds) = z4;
        *(float4*)(ldsS + SBUF + s1Lds) = z4;
    }
    if (s2Act && !s2In) {
        *(float4*)(ldsS + s2Lds) = z4;
        *(float4*)(ldsS + SBUF + s2Lds) = z4;
    }

    // ---- S pipeline: register prefetch + double-buffered LDS ----
    float4 ps0, ps1, ps2;
    const float* s0Next = s0Ptr0;
    const float* s1Next = s1Ptr0;
    const float* s2Next = s2Ptr0;

    auto loadS = [&]() {
        if (s0In) ps0 = *(const float4*)s0Next;
        if (s1In) ps1 = *(const float4*)s1Next;
        if (s2In) ps2 = *(const float4*)s2Next;
        s0Next += chunkStep;
        s1Next += chunkStep;
        s2Next += chunkStep;
    };
    auto writeS = [&](int half) {
        float* wS = ldsS + half * SBUF;
        if (s0In) *(float4*)(wS + s0Lds) = ps0;
        if (s1In) *(float4*)(wS + s1Lds) = ps1;
        if (s2In) *(float4*)(wS + s2Lds) = ps2;
    };

    // ---- accumulators ----
    float acc[WINW][4];
    #pragma unroll
    for (int dx = 0; dx < WINW; ++dx)
        #pragma unroll
        for (int j = 0; j < 4; ++j) acc[dx][j] = 0.f;

    // ---- pipelined main loop: 1 barrier per chunk ----
    loadS();             // chunk 0 -> regs
    writeS(0);           // chunk 0 -> LDS half 0
    loadS();             // chunk 1 -> regs
    __syncthreads();

    // wave widx computes dy = d0 + widx -> staged row (yth + widx).
    // own quad = staged quad (xg+1); halo quad: xg==0 -> quad 0, xg==15 -> 17.
    const int rowQ   = (yth + widx) * (SCOLS / 4);            // quad idx of row
    const int ownQ   = rowQ + (xg + 1);
    const int haloQ  = rowQ + ((xg == 0) ? 0 : (xg == 15) ? 17 : (xg + 1));

    for (int k = 0; k < NCHUNK; ++k) {
        // F for this chunk: 4 global loads (L1-hot: shared by all 3 waves)
        float4 fr[CC];
        #pragma unroll
        for (int cc = 0; cc < CC; ++cc)
            fr[cc] = *(const float4*)(fp + (long)cc * planeHW);
        fp += chunkStep;

        const int cur = k & 1;
        if (k + 1 < NCHUNK) {
            writeS(cur ^ 1);                 // chunk k+1 regs -> other half
            if (k + 2 < NCHUNK) loadS();     // issue chunk k+2 loads
        }

        // compute chunk k from LDS half cur: 2 ds_read_b128 + 8 DPP + 36 FMA
        const float* hb = ldsS + cur * SBUF;
        #pragma unroll
        for (int cc = 0; cc < CC; ++cc) {
            const float4 s4 = *(const float4*)(hb + 4 * (cc * Q_CH + ownQ));
            const float4 h4 = *(const float4*)(hb + 4 * (cc * Q_CH + haloQ));
            float wv[12];
            wv[0] = dpp_mov<0x111>(h4.x, s4.x);   // left quad from lane xg-1
            wv[1] = dpp_mov<0x111>(h4.y, s4.y);
            wv[2] = dpp_mov<0x111>(h4.z, s4.z);
            wv[3] = dpp_mov<0x111>(h4.w, s4.w);
            wv[4] = s4.x; wv[5] = s4.y; wv[6] = s4.z; wv[7] = s4.w;
            wv[8]  = dpp_mov<0x101>(h4.x, s4.x);  // right quad from lane xg+1
            wv[9]  = dpp_mov<0x101>(h4.y, s4.y);
            wv[10] = dpp_mov<0x101>(h4.z, s4.z);
            wv[11] = dpp_mov<0x101>(h4.w, s4.w);
            const float4 f = fr[cc];
            #pragma unroll
            for (int dx = 0; dx < WINW; ++dx) {
                acc[dx][0] += f.x * wv[dx + 0];
                acc[dx][1] += f.y * wv[dx + 1];
                acc[dx][2] += f.z * wv[dx + 2];
                acc[dx][3] += f.w * wv[dx + 3];
            }
        }

        if (k + 1 < NCHUNK) __syncthreads();
    }

    // ---- epilogue: 9 coalesced float4 stores (disjoint ownership) ----
    const float scale = 1.0f / (float)C_;
    const int dy = d0 + widx;
    const int fRow = y0 + yth;
    #pragma unroll
    for (int dx = 0; dx < WINW; ++dx) {
        float4 o;
        o.x = acc[dx][0] * scale;
        o.y = acc[dx][1] * scale;
        o.z = acc[dx][2] * scale;
        o.w = acc[dx][3] * scale;
        const int d = dy * WINW + dx;
        float* dst = O + ((long)(b * NDISP + d) * H_ + fRow) * W_ + x0 + 4 * xg;
        *(float4*)dst = o;
    }
}

extern "C" void kernel_launch(void* const* d_in, const int* in_sizes, int n_in,
                              void* d_out, int out_size, void* d_ws, size_t ws_size,
                              hipStream_t stream) {
    const float* F = (const float*)d_in[0];
    const float* S = (const float*)d_in[1];
    float* O = (float*)d_out;
    dim3 grid(NBLK, 1, 1);   // 1728 three-wave blocks
    dim3 block(NTHREADS);
    corr_kernel<<<grid, block, 0, stream>>>(F, S, O);
}

// Round 9
// 392.972 us; speedup vs baseline: 2.2388x; 1.0017x over previous
//
#include <hip/hip_runtime.h>

// Correlation cost volume: B=4, C=256, H=W=192, MAX_DISP=4 -> 81 displacements.
// out[b, dy*9+dx, y, x] = (1/C) * sum_c F[b,c,y,x] * Spad[b,c,y+dy-4,x+dx-4]
//
// R9 = R3 structure (best: 187us; 3-wave dy-split blocks, S double-buffered in
//     LDS, F global-direct, 3 ds_read_b128/channel) + XCD swizzle (R8-proven,
//     FETCH 318->216MB) + RAW BARRIERS: __syncthreads() emits
//     s_waitcnt vmcnt(0) before s_barrier, draining the 3-load S prefetch
//     queue every chunk (64x/block). Only LDS visibility is required there:
//     use s_waitcnt lgkmcnt(0) + s_barrier, leaving global loads in flight
//     across the barrier (T3/T4 counted-vmcnt discipline; HK pattern).
//     R8 lessons: DPP reverted (VALU cost > LDS saving); LDS "conflict"
//     counter is ~5cyc/b128 instruction-proportional overhead, not pattern.

#define MAXD 4
#define WINW 9
#define NDISP 81

constexpr int B_ = 4, C_ = 256, H_ = 192, W_ = 192;
constexpr int TH = 4;                    // output rows per block
constexpr int TW = 64;                   // output cols per block
constexpr int DYS = 3;                   // dy values per block
constexpr int NDY = WINW / DYS;          // 3 dy groups
constexpr int CC = 4;                    // channels staged per chunk
constexpr int NCHUNK = C_ / CC;          // 64
constexpr int SROWS = TH + DYS - 1;      // 6 staged S rows
constexpr int SCOLS = TW + 2 * MAXD;     // 72
constexpr int S_STRIDE = 72;             // floats per staged row
constexpr int S_CH = SROWS * S_STRIDE;   // 432 floats per staged channel
constexpr int SBUF = CC * S_CH;          // 1728 floats per half
constexpr int NTHREADS = 64 * DYS;       // 192 threads = 3 waves
constexpr int NS4 = CC * SROWS * (SCOLS / 4);   // 432 float4 per chunk
constexpr int Q_CH = SROWS * (SCOLS / 4);       // 108 float4 per channel
constexpr int NTX = W_ / TW;             // 3
constexpr int NTY = H_ / TH;             // 48
constexpr int NZ = B_ * NDY;             // 12
constexpr int NBLK = NTX * NTY * NZ;     // 1728
constexpr int PER_XCD = NBLK / 8;        // 216 (exact)
constexpr int PHW = H_ * W_;             // 36864

// Workgroup barrier with LDS-only visibility: does NOT drain vmcnt, so the
// register-destined global prefetches stay in flight across it.
__device__ __forceinline__ void wg_barrier_lds() {
    asm volatile("s_waitcnt lgkmcnt(0)" ::: "memory");
    __builtin_amdgcn_s_barrier();
    asm volatile("" ::: "memory");   // no memory op crosses the barrier upward
}

__global__ __launch_bounds__(NTHREADS)
void corr_kernel(const float* __restrict__ F, const float* __restrict__ S,
                 float* __restrict__ O) {
    __shared__ __align__(16) float ldsS[2 * SBUF];   // 13.8 KB

    const int tid  = threadIdx.x;

    // ---- XCD-bijective swizzle: XCD k owns 18 tiles x 12 z-variants ----
    const int id   = blockIdx.x;
    const int lg   = (id & 7) * PER_XCD + (id >> 3);
    const int tile = lg / NZ;
    const int zb   = lg - tile * NZ;
    const int b    = zb / NDY;           // batch
    const int d0   = (zb - b * NDY) * DYS;  // first dy of this block
    const int ty   = tile / NTX;
    const int tx   = tile - ty * NTX;
    const int y0 = ty * TH, x0 = tx * TW;

    const int widx = tid >> 6;           // wave index: dy = d0 + widx
    const int lane = tid & 63;
    const int xg   = lane & 15;          // x-group of 4 px
    const int yth  = lane >> 4;          // row within tile, [0,4)

    const long planeHW   = (long)PHW;
    const long chunkStep = (long)CC * planeHW;
    const float* Fb = F + (long)b * C_ * planeHW;
    const float* Sb = S + (long)b * C_ * planeHW;

    // ---- F: direct per-thread global pointer (same px for all 3 waves) ----
    const float* fp = Fb + (long)(y0 + yth) * W_ + (x0 + 4 * xg);

    // ---- chunk-invariant S staging decomposition (3 slots / thread) ----
    const int ybase = y0 + d0 - MAXD;    // first staged S row

    // slot 0: i = tid (always active)
    const int  s0cc  = tid / Q_CH;
    const int  s0rem = tid - s0cc * Q_CH;
    const int  s0r   = s0rem / (SCOLS / 4);
    const int  s0cg  = s0rem - s0r * (SCOLS / 4);
    const int  s0ys  = ybase + s0r;
    const int  s0xs  = x0 - MAXD + 4 * s0cg;
    const bool s0In  = ((unsigned)s0ys < (unsigned)H_) &&
                       ((unsigned)s0xs <= (unsigned)(W_ - 4));
    const int  s0Lds = s0cc * S_CH + s0r * S_STRIDE + 4 * s0cg;
    const float* s0Ptr0 = Sb + (long)s0cc * planeHW + (long)s0ys * W_ + s0xs;

    // slot 1: i = tid + 192 (always active: i in [192,384) < 432)
    const int  i1    = tid + NTHREADS;
    const int  s1cc  = i1 / Q_CH;
    const int  s1rem = i1 - s1cc * Q_CH;
    const int  s1r   = s1rem / (SCOLS / 4);
    const int  s1cg  = s1rem - s1r * (SCOLS / 4);
    const int  s1ys  = ybase + s1r;
    const int  s1xs  = x0 - MAXD + 4 * s1cg;
    const bool s1In  = ((unsigned)s1ys < (unsigned)H_) &&
                       ((unsigned)s1xs <= (unsigned)(W_ - 4));
    const int  s1Lds = s1cc * S_CH + s1r * S_STRIDE + 4 * s1cg;
    const float* s1Ptr0 = Sb + (long)s1cc * planeHW + (long)s1ys * W_ + s1xs;

    // slot 2: i = tid + 384, active for tid < 48
    const int  i2    = tid + 2 * NTHREADS;
    const bool s2Act = (i2 < NS4);
    const int  s2cc  = i2 / Q_CH;
    const int  s2rem = i2 - s2cc * Q_CH;
    const int  s2r   = s2rem / (SCOLS / 4);
    const int  s2cg  = s2rem - s2r * (SCOLS / 4);
    const int  s2ys  = ybase + s2r;
    const int  s2xs  = x0 - MAXD + 4 * s2cg;
    const bool s2In  = s2Act && ((unsigned)s2ys < (unsigned)H_) &&
                       ((unsigned)s2xs <= (unsigned)(W_ - 4));
    const int  s2Lds = s2cc * S_CH + s2r * S_STRIDE + 4 * s2cg;
    const float* s2Ptr0 = Sb + (long)s2cc * planeHW + (long)s2ys * W_ + s2xs;

    // ---- zero the OOB halo slots ONCE (both halves) ----
    const float4 z4 = make_float4(0.f, 0.f, 0.f, 0.f);
    if (!s0In) {
        *(float4*)(ldsS + s0Lds) = z4;
        *(float4*)(ldsS + SBUF + s0Lds) = z4;
    }
    if (!s1In) {
        *(float4*)(ldsS + s1Lds) = z4;
        *(float4*)(ldsS + SBUF + s1Lds) = z4;
    }
    if (s2Act && !s2In) {
        *(float4*)(ldsS + s2Lds) = z4;
        *(float4*)(ldsS + SBUF + s2Lds) = z4;
    }

    // ---- S pipeline: register prefetch + double-buffered LDS ----
    float4 ps0, ps1, ps2;
    const float* s0Next = s0Ptr0;
    const float* s1Next = s1Ptr0;
    const float* s2Next = s2Ptr0;

    auto loadS = [&]() {
        if (s0In) ps0 = *(const float4*)s0Next;
        if (s1In) ps1 = *(const float4*)s1Next;
        if (s2In) ps2 = *(const float4*)s2Next;
        s0Next += chunkStep;
        s1Next += chunkStep;
        s2Next += chunkStep;
    };
    auto writeS = [&](int half) {
        float* wS = ldsS + half * SBUF;
        if (s0In) *(float4*)(wS + s0Lds) = ps0;
        if (s1In) *(float4*)(wS + s1Lds) = ps1;
        if (s2In) *(float4*)(wS + s2Lds) = ps2;
    };

    // ---- accumulators ----
    float acc[WINW][4];
    #pragma unroll
    for (int dx = 0; dx < WINW; ++dx)
        #pragma unroll
        for (int j = 0; j < 4; ++j) acc[dx][j] = 0.f;

    // ---- pipelined main loop: 1 raw barrier per chunk ----
    loadS();             // chunk 0 -> regs
    writeS(0);           // chunk 0 -> LDS half 0
    loadS();             // chunk 1 -> regs (stays in flight across barrier)
    wg_barrier_lds();

    // wave widx computes dy = d0 + widx -> staged row (yth + widx)
    const float* bS0 = ldsS + (yth + widx) * S_STRIDE + 4 * xg;

    for (int k = 0; k < NCHUNK; ++k) {
        // F for this chunk: 4 global loads (L1-hot: shared by all 3 waves)
        float4 fr[CC];
        #pragma unroll
        for (int cc = 0; cc < CC; ++cc)
            fr[cc] = *(const float4*)(fp + (long)cc * planeHW);
        fp += chunkStep;

        const int cur = k & 1;
        if (k + 1 < NCHUNK) {
            writeS(cur ^ 1);                 // chunk k+1 regs -> other half
            if (k + 2 < NCHUNK) loadS();     // issue chunk k+2 loads
        }

        // compute chunk k from LDS half cur: 3 ds_read_b128 + 36 FMA /channel
        const float* bS = bS0 + cur * SBUF;
        #pragma unroll
        for (int cc = 0; cc < CC; ++cc) {
            const float4 f  = fr[cc];
            const float4 w0 = *(const float4*)(bS + cc * S_CH);
            const float4 w1 = *(const float4*)(bS + cc * S_CH + 4);
            const float4 w2 = *(const float4*)(bS + cc * S_CH + 8);
            const float w[12] = {w0.x, w0.y, w0.z, w0.w,
                                 w1.x, w1.y, w1.z, w1.w,
                                 w2.x, w2.y, w2.z, w2.w};
            #pragma unroll
            for (int dx = 0; dx < WINW; ++dx) {
                acc[dx][0] += f.x * w[dx];
                acc[dx][1] += f.y * w[dx + 1];
                acc[dx][2] += f.z * w[dx + 2];
                acc[dx][3] += f.w * w[dx + 3];
            }
        }

        // LDS-only barrier: reads of half cur drained (lgkmcnt covers them),
        // writes to half cur^1 visible; global prefetches remain in flight.
        if (k + 1 < NCHUNK) wg_barrier_lds();
    }

    // ---- epilogue: 9 coalesced float4 stores (disjoint ownership) ----
    const float scale = 1.0f / (float)C_;
    const int dy = d0 + widx;
    const int fRow = y0 + yth;
    #pragma unroll
    for (int dx = 0; dx < WINW; ++dx) {
        float4 o;
        o.x = acc[dx][0] * scale;
        o.y = acc[dx][1] * scale;
        o.z = acc[dx][2] * scale;
        o.w = acc[dx][3] * scale;
        const int d = dy * WINW + dx;
        float* dst = O + ((long)(b * NDISP + d) * H_ + fRow) * W_ + x0 + 4 * xg;
        *(float4*)dst = o;
    }
}

extern "C" void kernel_launch(void* const* d_in, const int* in_sizes, int n_in,
                              void* d_out, int out_size, void* d_ws, size_t ws_size,
                              hipStream_t stream) {
    const float* F = (const float*)d_in[0];
    const float* S = (const float*)d_in[1];
    float* O = (float*)d_out;
    dim3 grid(NBLK, 1, 1);   // 1728 three-wave blocks
    dim3 block(NTHREADS);
    corr_kernel<<<grid, block, 0, stream>>>(F, S, O);
}